// Round 13
// baseline (237.693 us; speedup 1.0000x reference)
//
#include <hip/hip_runtime.h>

#define N_TOT  400000
#define NTILE  25000        // N_TOT / 16 voxels per tile
#define NELEM  (N_TOT * 16)
#define CBLK   512          // persistent conv blocks (2 per CU)
#define GS     (CBLK * 4)   // wave grid stride (tiles)

typedef __attribute__((ext_vector_type(8))) short short8;
typedef __attribute__((ext_vector_type(4))) float f32x4;
typedef __attribute__((ext_vector_type(4))) unsigned short us4;

__device__ __forceinline__ unsigned short f2bf(float x) {
    unsigned int u = __float_as_uint(x);
    u += 0x7FFFu + ((u >> 16) & 1u);       // round-to-nearest-even
    return (unsigned short)(u >> 16);
}
__device__ __forceinline__ float bf2f(unsigned short h) {
    return __uint_as_float(((unsigned int)h) << 16);
}

// Build bf16 B-fragments for all 5 layers x 14 k-pairs, and zero the pad voxel
// (index N_TOT) in both bf16 gather buffers.
// mfma_f32_16x16x32_bf16 B layout: lane l holds B[k=8*(l>>4)+j][col=l&15].
__global__ __launch_bounds__(64) void wfrag_k(const float* __restrict__ w_in,
                                              const float* __restrict__ wbs,
                                              unsigned short* __restrict__ wfrag,
                                              unsigned short* __restrict__ xb,
                                              unsigned short* __restrict__ ob) {
    if (blockIdx.x == 0 && threadIdx.x < 8) {
        us4 z = {0, 0, 0, 0};
        unsigned short* base = (threadIdx.x < 4) ? xb : ob;
        reinterpret_cast<us4*>(base + NELEM)[threadIdx.x & 3] = z;
    }
    int b = blockIdx.x;            // L*14 + p
    int L = b / 14, p = b % 14;
    int l = threadIdx.x;
    int g = l >> 4, col = l & 15;
    int k = 2 * p + (g >> 1);
    int cib = (g & 1) * 8;
    unsigned short v[8];
#pragma unroll
    for (int j = 0; j < 8; ++j) {
        float w = 0.f;
        if (k < 27) {
            int ci = cib + j;
            w = (L == 0) ? w_in[(k * 16 + ci) * 16 + col]
                         : wbs[(((L - 1) * 27 + k) * 16 + ci) * 16 + col];
        }
        v[j] = f2bf(w);
    }
    unsigned short* dst = wfrag + (size_t)(b * 64 + l) * 8;
#pragma unroll
    for (int j = 0; j < 8; ++j) dst[j] = v[j];
}

// Compressed rulebook, built once (owner-computes, no atomics).
// Per tile t: header 128B = masks[16] u32 (bit k set iff offset k valid,
// k=13 excluded) | voxoff[16] u8 (exclusive prefix of per-voxel counts) | pad.
// Compacted neighbor indices: cidx[t*64 + voxoff[rc] + rank], rank = popcount
// of lower valid bits. Max 64 valid/tile (mean 14.4, +13 sigma) - safe.
__global__ __launch_bounds__(256) void build_k(const int* __restrict__ nbr,
                                               int* __restrict__ thdr,
                                               int* __restrict__ cidx) {
    int tid = threadIdx.x;
    int lane16 = tid & 15;
    int t = blockIdx.x * 16 + (tid >> 4);
    if (t >= NTILE) return;
    int v = t * 16 + lane16;
    unsigned mask = 0;
    int vals[26];
#pragma unroll
    for (int k = 0; k < 27; ++k) {
        if (k == 13) continue;
        int slot = k < 13 ? k : k - 1;
        int in_v = nbr[(size_t)k * N_TOT + v];
        vals[slot] = in_v;
        if (in_v >= 0) mask |= (1u << k);
    }
    int cnt = __popc(mask);
    int pref = cnt;
#pragma unroll
    for (int d = 1; d < 16; d <<= 1) {
        int n = __shfl_up(pref, d, 16);
        if (lane16 >= d) pref += n;
    }
    int vo = pref - cnt;               // exclusive prefix within tile
    int* hp = thdr + t * 32;           // 128 B = 32 ints
    hp[lane16] = (int)mask;
    *((unsigned char*)(hp + 16) + lane16) = (unsigned char)vo;
    int pos = t * 64 + vo;
#pragma unroll
    for (int k = 0; k < 27; ++k) {
        if (k == 13) continue;
        int slot = k < 13 ? k : k - 1;
        if (mask & (1u << k)) cidx[pos++] = vals[slot];
    }
}

__global__ __launch_bounds__(256) void cvt_k(const float* __restrict__ in,
                                             unsigned short* __restrict__ out) {
    int i = (blockIdx.x * 256 + threadIdx.x) * 8;
    f32x4 a = *reinterpret_cast<const f32x4*>(in + i);
    f32x4 b = *reinterpret_cast<const f32x4*>(in + i + 4);
    short8 o = { (short)f2bf(a[0]), (short)f2bf(a[1]), (short)f2bf(a[2]), (short)f2bf(a[3]),
                 (short)f2bf(b[0]), (short)f2bf(b[1]), (short)f2bf(b[2]), (short)f2bf(b[3]) };
    *reinterpret_cast<short8*>(out + i) = o;
}

// Persistent gather-MFMA conv, 4-stage decoupled pipeline per wave:
//   header(t+2S) | cidx->I (t+2S after hdr) / gathers(t+S) | MFMA+store(t).
// IDX phase touches ~4 cache lines/tile (2 header + ~2 compacted data) vs 52
// for the raw 41.6MB nbr stream - the line-traffic experiment. Dense I[] is
// reconstructed in-register via popcount ranking. Straight-line lane work.
// Center (k=13) = identity. Invalid -> zero voxel at N_TOT.
#define IDXH(Hm, Hv, tt)                                                        \
  {                                                                             \
    const char* hp = (const char*)thdr + ((size_t)(tt) << 7);                   \
    Hm = *reinterpret_cast<const int*>(hp + (rc << 2));                         \
    Hv = *(const unsigned char*)(hp + 64 + rc);                                 \
  }

#define IDXD(I, Hm, Hv, tt)                                                     \
  {                                                                             \
    int cbase = ((tt) << 6) + Hv;                                               \
    _Pragma("unroll")                                                           \
    for (int p = 0; p < 14; ++p) {                                              \
      int k = 2 * p + ksel;                                                     \
      if (k == 13) I[p] = ((tt) << 4) + rc;                                     \
      else if (k < 27) {                                                        \
        unsigned below = ((unsigned)Hm) & ((kb << (2 * p)) - 1u);               \
        int tmp = cidx[cbase + __popc(below)];                                  \
        I[p] = ((Hm >> k) & 1) ? tmp : -1;                                      \
      } else I[p] = -1;                                                         \
    }                                                                           \
  }

#define GAT(A, I)                                                               \
  {                                                                             \
    _Pragma("unroll")                                                           \
    for (int p = 0; p < 14; ++p) {                                              \
      int ci = I[p] < 0 ? N_TOT : I[p];                                         \
      A[p] = *reinterpret_cast<const short8*>(feats + ((size_t)ci << 4) + half);\
    }                                                                           \
  }

#define CMP(A, tt)                                                              \
  {                                                                             \
    f32x4 ac0 = {0.f, 0.f, 0.f, 0.f};                                           \
    f32x4 ac1 = {0.f, 0.f, 0.f, 0.f};                                           \
    _Pragma("unroll")                                                           \
    for (int p = 0; p < 14; p += 2) {                                           \
      short8 b0 = *reinterpret_cast<const short8*>(&wlds[(p * 64 + lane) * 8]); \
      short8 b1 = *reinterpret_cast<const short8*>(&wlds[((p + 1) * 64 + lane) * 8]); \
      ac0 = __builtin_amdgcn_mfma_f32_16x16x32_bf16(A[p],     b0, ac0, 0, 0, 0);\
      ac1 = __builtin_amdgcn_mfma_f32_16x16x32_bf16(A[p + 1], b1, ac1, 0, 0, 0);\
    }                                                                           \
    f32x4 acc = ac0 + ac1;                                                      \
    const int vv = (tt) * 16;                                                   \
    _Pragma("unroll")                                                           \
    for (int i = 0; i < 4; ++i)                                                 \
      raw[(size_t)(vv + g * 4 + i) * 16 + rc] = f2bf(acc[i]);                   \
    s_acc += acc[0] + acc[1] + acc[2] + acc[3];                                 \
    q_acc += acc[0]*acc[0] + acc[1]*acc[1] + acc[2]*acc[2] + acc[3]*acc[3];     \
  }

__global__ __launch_bounds__(256, 2) void conv_k(const unsigned short* __restrict__ feats,
                                                 const int* __restrict__ thdr,
                                                 const int* __restrict__ cidx,
                                                 const unsigned short* __restrict__ wfrag,
                                                 unsigned short* __restrict__ raw,
                                                 float* __restrict__ partials) {
    __shared__ unsigned short wlds[14 * 64 * 8];   // 14336 B
    __shared__ float red[128];

    {   // cooperative W stage: 14336 B = 896 x 16 B (once per block)
        const f32x4* src = reinterpret_cast<const f32x4*>(wfrag);
        f32x4* dst = reinterpret_cast<f32x4*>(wlds);
        for (int j = threadIdx.x; j < 896; j += 256) dst[j] = src[j];
    }
    __syncthreads();

    const int lane = threadIdx.x & 63;
    const int wv   = threadIdx.x >> 6;
    const int g    = lane >> 4;
    const int rc   = lane & 15;        // A-row / B-col
    const int half = (g & 1) * 8;      // which 8 input channels this lane loads
    const int ksel = g >> 1;           // which offset of the pair
    const unsigned kb = 1u << ksel;    // (kb<<2p)-1 == (1<<(2p+ksel))-1

    float s_acc = 0.f, q_acc = 0.f;

    int Ham, Hav, Hbm, Hbv;
    int Ia[14], Ib[14];
    short8 Aa[14], Ab[14];

    int t  = blockIdx.x * 4 + wv;
    int t1 = t + GS, t2 = t + 2 * GS;
    IDXH(Ham, Hav, t);
    IDXD(Ia, Ham, Hav, t);             // exposed hdr stall, prologue only
    GAT(Aa, Ia);                       // exposed cidx stall, prologue only
    if (t1 < NTILE) { IDXH(Hbm, Hbv, t1); IDXD(Ib, Hbm, Hbv, t1); }
    if (t2 < NTILE) IDXH(Ham, Hav, t2);

    for (;;) {
        // state: A=Aa(t), I=Ib(t+S), H=Ha(t+2S)
        int t3 = t + 3 * GS;
        if (t3 < NTILE) IDXH(Hbm, Hbv, t3);
        if (t2 < NTILE) IDXD(Ia, Ham, Hav, t2);
        if (t1 < NTILE) GAT(Ab, Ib);
        __builtin_amdgcn_sched_barrier(0);
        CMP(Aa, t);
        if (t1 >= NTILE) break;
        t = t1; t1 = t + GS; t2 = t + 2 * GS; t3 = t + 3 * GS;

        // state: A=Ab(t), I=Ia(t+S), H=Hb(t+2S)
        if (t3 < NTILE) IDXH(Ham, Hav, t3);
        if (t2 < NTILE) IDXD(Ib, Hbm, Hbv, t2);
        if (t1 < NTILE) GAT(Aa, Ia);
        __builtin_amdgcn_sched_barrier(0);
        CMP(Ab, t);
        if (t1 >= NTILE) break;
        t = t1; t1 = t + GS; t2 = t + 2 * GS;
    }

    // BN partials: per-channel sum & sumsq over all tiles this block touched
    s_acc += __shfl_xor(s_acc, 16);  s_acc += __shfl_xor(s_acc, 32);
    q_acc += __shfl_xor(q_acc, 16);  q_acc += __shfl_xor(q_acc, 32);
    if (lane < 16) {
        red[wv * 32 + rc]      = s_acc;
        red[wv * 32 + 16 + rc] = q_acc;
    }
    __syncthreads();
    if (threadIdx.x < 32) {
        float v = red[threadIdx.x] + red[32 + threadIdx.x] +
                  red[64 + threadIdx.x] + red[96 + threadIdx.x];
        partials[(size_t)threadIdx.x * CBLK + blockIdx.x] = v;
    }
}

__global__ __launch_bounds__(256) void reduce_k(const float* __restrict__ partials,
                                                float* __restrict__ S) {
    int c = blockIdx.x;  // 0..31 (16 sums, 16 sumsqs)
    float s = 0.f;
    for (int i = threadIdx.x; i < CBLK; i += 256) s += partials[(size_t)c * CBLK + i];
    __shared__ float red[256];
    red[threadIdx.x] = s;
    __syncthreads();
#pragma unroll
    for (int off = 128; off > 0; off >>= 1) {
        if (threadIdx.x < off) red[threadIdx.x] += red[threadIdx.x + off];
        __syncthreads();
    }
    if (threadIdx.x == 0) S[c] = red[0];
}

// BN finalize fused; reads raw bf16 conv output, optional bf16 residual,
// writes bf16 feature buffer and/or f32 final output. 8 elems/thread.
__global__ __launch_bounds__(256) void apply_k(const unsigned short* __restrict__ raw,
                                               const float* __restrict__ S,
                                               const float* __restrict__ gamma,
                                               const float* __restrict__ beta,
                                               const unsigned short* residb,
                                               unsigned short* bfout,
                                               float* f32out) {
    int i = (blockIdx.x * 256 + threadIdx.x) * 8;
    int c0 = i & 8;                    // channels c0..c0+7
    short8 r8 = *reinterpret_cast<const short8*>(raw + i);
    float res[8] = {0, 0, 0, 0, 0, 0, 0, 0};
    if (residb) {
        short8 x8 = *reinterpret_cast<const short8*>(residb + i);
#pragma unroll
        for (int j = 0; j < 8; ++j) res[j] = bf2f((unsigned short)x8[j]);
    }
    const float inv = 1.0f / (float)N_TOT;
    float val[8];
#pragma unroll
    for (int j = 0; j < 8; ++j) {
        int c = c0 + j;
        float m   = S[c] * inv;
        float var = S[16 + c] * inv - m * m;
        float sc  = gamma[c] * rsqrtf(var + 1e-3f);
        float sh  = beta[c] - m * sc;
        val[j] = fmaxf(bf2f((unsigned short)r8[j]) * sc + sh + res[j], 0.f);
    }
    if (bfout) {
        short8 o = { (short)f2bf(val[0]), (short)f2bf(val[1]), (short)f2bf(val[2]), (short)f2bf(val[3]),
                     (short)f2bf(val[4]), (short)f2bf(val[5]), (short)f2bf(val[6]), (short)f2bf(val[7]) };
        *reinterpret_cast<short8*>(bfout + i) = o;
    }
    if (f32out) {
        f32x4 lo = { val[0], val[1], val[2], val[3] };
        f32x4 hi = { val[4], val[5], val[6], val[7] };
        *reinterpret_cast<f32x4*>(f32out + i)     = lo;
        *reinterpret_cast<f32x4*>(f32out + i + 4) = hi;
    }
}

extern "C" void kernel_launch(void* const* d_in, const int* in_sizes, int n_in,
                              void* d_out, int out_size, void* d_ws, size_t ws_size,
                              hipStream_t stream) {
    const float* vf   = (const float*)d_in[0];
    const int*   nbr  = (const int*)  d_in[1];
    const float* w_in = (const float*)d_in[2];
    const float* g_in = (const float*)d_in[3];
    const float* b_in = (const float*)d_in[4];
    const float* wbs  = (const float*)d_in[5];
    const float* gs   = (const float*)d_in[6];
    const float* bs   = (const float*)d_in[7];
    float* out = (float*)d_out;

    char* ws = (char*)d_ws;
    size_t off = 0;
    auto alloc = [&](size_t b) { char* p = ws + off; off += (b + 255) & ~(size_t)255; return p; };
    unsigned short* wfrag = (unsigned short*)alloc((size_t)5 * 14 * 64 * 8 * 2);
    unsigned short* xb    = (unsigned short*)alloc((size_t)(NELEM + 16) * 2);  // bf16 x (+zero voxel)
    unsigned short* ob    = (unsigned short*)alloc((size_t)(NELEM + 16) * 2);  // bf16 o (+zero voxel)
    unsigned short* rb    = (unsigned short*)alloc((size_t)NELEM * 2);         // bf16 raw conv out
    int*            thdr  = (int*)alloc((size_t)NTILE * 128);                  // 3.2 MB headers
    int*            cidx  = (int*)alloc(((size_t)NTILE * 64 + 64) * 4);        // 6.4 MB compacted idx
    float*          part  = (float*)alloc((size_t)32 * CBLK * 4);
    float*          S     = (float*)alloc(32 * 4);

    const int FR = 14 * 64 * 8;  // ushorts per layer of wfrag

    wfrag_k<<<70, 64, 0, stream>>>(w_in, wbs, wfrag, xb, ob);
    build_k<<<1563, 256, 0, stream>>>(nbr, thdr, cidx);
    cvt_k<<<3125, 256, 0, stream>>>(vf, xb);

    // L0: x0 = relu(bn(conv(vf)))                 -> xb
    conv_k<<<CBLK, 256, 0, stream>>>(xb, thdr, cidx, wfrag, rb, part);
    reduce_k<<<32, 256, 0, stream>>>(part, S);
    apply_k<<<3125, 256, 0, stream>>>(rb, S, g_in, b_in, nullptr, xb, nullptr);

    // L1: o = relu(bn(conv(x0)))                  -> ob
    conv_k<<<CBLK, 256, 0, stream>>>(xb, thdr, cidx, wfrag + FR, rb, part);
    reduce_k<<<32, 256, 0, stream>>>(part, S);
    apply_k<<<3125, 256, 0, stream>>>(rb, S, gs + 0, bs + 0, nullptr, ob, nullptr);

    // L2: x1 = relu(bn(conv(o)) + x0)             -> xb (in place resid)
    conv_k<<<CBLK, 256, 0, stream>>>(ob, thdr, cidx, wfrag + 2 * FR, rb, part);
    reduce_k<<<32, 256, 0, stream>>>(part, S);
    apply_k<<<3125, 256, 0, stream>>>(rb, S, gs + 16, bs + 16, xb, xb, nullptr);

    // L3: o = relu(bn(conv(x1)))                  -> ob
    conv_k<<<CBLK, 256, 0, stream>>>(xb, thdr, cidx, wfrag + 3 * FR, rb, part);
    reduce_k<<<32, 256, 0, stream>>>(part, S);
    apply_k<<<3125, 256, 0, stream>>>(rb, S, gs + 32, bs + 32, nullptr, ob, nullptr);

    // L4: out = relu(bn(conv(o)) + x1)            -> d_out (f32)
    conv_k<<<CBLK, 256, 0, stream>>>(ob, thdr, cidx, wfrag + 4 * FR, rb, part);
    reduce_k<<<32, 256, 0, stream>>>(part, S);
    apply_k<<<3125, 256, 0, stream>>>(rb, S, gs + 48, bs + 48, xb, nullptr, out);
}

// Round 14
// 181.352 us; speedup vs baseline: 1.3107x; 1.3107x over previous
//
#include <hip/hip_runtime.h>

#define N_TOT  400000
#define NTILE  25000        // N_TOT / 16 voxels per tile
#define NELEM  (N_TOT * 16)
#define CBLK   512          // persistent conv blocks (2 per CU)
#define GS     (CBLK * 4)   // wave grid stride (tiles)
#define PKB    1152         // packed rulebook bytes per tile (18 lines)

typedef __attribute__((ext_vector_type(8))) short short8;
typedef __attribute__((ext_vector_type(4))) float f32x4;
typedef __attribute__((ext_vector_type(4))) unsigned short us4;

__device__ __forceinline__ unsigned short f2bf(float x) {
    unsigned int u = __float_as_uint(x);
    u += 0x7FFFu + ((u >> 16) & 1u);       // round-to-nearest-even
    return (unsigned short)(u >> 16);
}
__device__ __forceinline__ float bf2f(unsigned short h) {
    return __uint_as_float(((unsigned int)h) << 16);
}

// Packed rulebook, built once. Per tile t (1152B, 64B-aligned):
//   rows k=0..27: u16 low16(id) at k*32 + rc*2   (28 rows x 32B)
//     k==13 -> own voxel id (identity); k==27 or invalid -> N_TOT (zero voxel)
//   hi bits: u64 at 896 + (ksel*16+rc)*8, bits[3p+2:3p] = id>>16 for k=2p+ksel
// Sentinel encoding kills all validity branches/cndmasks in the conv.
__global__ __launch_bounds__(256) void build_k(const int* __restrict__ nbr,
                                               char* __restrict__ pk) {
    int gt = blockIdx.x * 256 + threadIdx.x;
    if (gt >= N_TOT) return;
    int t = gt >> 4, rc = gt & 15;
    int v = gt;
    char* bp = pk + (size_t)t * PKB;
    unsigned long long hv0 = 0ull, hv1 = 0ull;
#pragma unroll
    for (int k = 0; k < 28; ++k) {
        int id;
        if (k == 13)      id = v;
        else if (k == 27) id = N_TOT;
        else {
            int n = nbr[(size_t)k * N_TOT + v];
            id = n < 0 ? N_TOT : n;
        }
        *reinterpret_cast<unsigned short*>(bp + k * 32 + rc * 2) =
            (unsigned short)(id & 0xFFFF);
        unsigned long long hi = (unsigned)(id >> 16);   // <= 6, fits 3 bits
        int p = k >> 1;
        if (k & 1) hv1 |= hi << (3 * p);
        else       hv0 |= hi << (3 * p);
    }
    *reinterpret_cast<unsigned long long*>(bp + 896 + rc * 8)       = hv0;
    *reinterpret_cast<unsigned long long*>(bp + 896 + 128 + rc * 8) = hv1;
}

// Merged prep: blocks 0..3124 cvt f32->bf16; 3125..3194 build W-fragments
// (mfma 16x16x32 B layout: lane l holds B[k=8*(l>>4)+j][col=l&15]);
// block 3195 zeroes the pad voxel in xb/ob.
__global__ __launch_bounds__(256) void prep_k(const float* __restrict__ vf,
                                              const float* __restrict__ w_in,
                                              const float* __restrict__ wbs,
                                              unsigned short* __restrict__ xb,
                                              unsigned short* __restrict__ ob,
                                              unsigned short* __restrict__ wfrag) {
    int b = blockIdx.x;
    if (b < 3125) {
        int i = (b * 256 + threadIdx.x) * 8;
        f32x4 a = *reinterpret_cast<const f32x4*>(vf + i);
        f32x4 c = *reinterpret_cast<const f32x4*>(vf + i + 4);
        short8 o = { (short)f2bf(a[0]), (short)f2bf(a[1]), (short)f2bf(a[2]), (short)f2bf(a[3]),
                     (short)f2bf(c[0]), (short)f2bf(c[1]), (short)f2bf(c[2]), (short)f2bf(c[3]) };
        *reinterpret_cast<short8*>(xb + i) = o;
    } else if (b < 3195) {
        if (threadIdx.x >= 64) return;
        int wb = b - 3125;               // L*14 + p
        int L = wb / 14, p = wb % 14;
        int l = threadIdx.x;
        int g = l >> 4, col = l & 15;
        int k = 2 * p + (g >> 1);
        int cib = (g & 1) * 8;
        unsigned short v[8];
#pragma unroll
        for (int j = 0; j < 8; ++j) {
            float w = 0.f;
            if (k < 27) {
                int ci = cib + j;
                w = (L == 0) ? w_in[(k * 16 + ci) * 16 + col]
                             : wbs[(((L - 1) * 27 + k) * 16 + ci) * 16 + col];
            }
            v[j] = f2bf(w);
        }
        unsigned short* dst = wfrag + (size_t)(wb * 64 + l) * 8;
#pragma unroll
        for (int j = 0; j < 8; ++j) dst[j] = v[j];
    } else {
        if (threadIdx.x < 8) {
            us4 z = {0, 0, 0, 0};
            unsigned short* base = (threadIdx.x < 4) ? xb : ob;
            reinterpret_cast<us4*>(base + NELEM)[threadIdx.x & 3] = z;
        }
    }
}

// Persistent gather-MFMA conv, 3-stage decoupled pipeline (champion structure):
//   idx loads tile t+2S | gathers tile t+S | MFMA+store tile t.
// IDX reads the packed rulebook: 14 independent u16 + 1 u64 = 18 lines/tile
// (was 26 from the raw nbr stream). Sentinel ids (center=self, invalid=zero
// voxel) make GAT a pure unpack+load, no cndmask. W-fragments in registers.
#define IDXP(L, HV, tt)                                                         \
  {                                                                             \
    const char* bp = pkc + (size_t)(tt) * PKB;                                  \
    HV = *reinterpret_cast<const unsigned long long*>(bp + hvoff);              \
    _Pragma("unroll")                                                           \
    for (int p = 0; p < 14; ++p)                                                \
      L[p] = *reinterpret_cast<const unsigned short*>(bp + (2 * p + ksel) * 32 + rc2); \
  }

#define GAT(A, L, HV)                                                           \
  {                                                                             \
    _Pragma("unroll")                                                           \
    for (int p = 0; p < 14; ++p) {                                              \
      int ci = (int)(L[p] | ((((unsigned)(HV >> (3 * p))) & 7u) << 16));        \
      A[p] = *reinterpret_cast<const short8*>(feats + ((size_t)ci << 4) + half);\
    }                                                                           \
  }

#define CMP(A, tt)                                                              \
  {                                                                             \
    f32x4 ac0 = {0.f, 0.f, 0.f, 0.f};                                           \
    f32x4 ac1 = {0.f, 0.f, 0.f, 0.f};                                           \
    _Pragma("unroll")                                                           \
    for (int p = 0; p < 14; p += 2) {                                           \
      ac0 = __builtin_amdgcn_mfma_f32_16x16x32_bf16(A[p],     B[p],     ac0, 0, 0, 0); \
      ac1 = __builtin_amdgcn_mfma_f32_16x16x32_bf16(A[p + 1], B[p + 1], ac1, 0, 0, 0); \
    }                                                                           \
    f32x4 acc = ac0 + ac1;                                                      \
    const int vv = (tt) * 16;                                                   \
    _Pragma("unroll")                                                           \
    for (int i = 0; i < 4; ++i)                                                 \
      raw[(size_t)(vv + g * 4 + i) * 16 + rc] = f2bf(acc[i]);                   \
    s_acc += acc[0] + acc[1] + acc[2] + acc[3];                                 \
    q_acc += acc[0]*acc[0] + acc[1]*acc[1] + acc[2]*acc[2] + acc[3]*acc[3];     \
  }

__global__ __launch_bounds__(256, 2) void conv_k(const unsigned short* __restrict__ feats,
                                                 const char* __restrict__ pkc,
                                                 const unsigned short* __restrict__ wfrag,
                                                 unsigned short* __restrict__ raw,
                                                 float* __restrict__ partials) {
    __shared__ float red[128];

    const int lane = threadIdx.x & 63;
    const int wv   = threadIdx.x >> 6;
    const int g    = lane >> 4;
    const int rc   = lane & 15;        // A-row / B-col
    const int half = (g & 1) * 8;      // which 8 input channels this lane loads
    const int ksel = g >> 1;           // which offset of the pair
    const int rc2  = rc * 2;
    const int hvoff = 896 + (ksel * 16 + rc) * 8;

    // loop-invariant W-fragments: 14 x short8 = 56 VGPRs, loaded once per wave
    short8 B[14];
#pragma unroll
    for (int p = 0; p < 14; ++p)
        B[p] = *reinterpret_cast<const short8*>(wfrag + (size_t)(p * 64 + lane) * 8);

    float s_acc = 0.f, q_acc = 0.f;

    unsigned L0[14], L1[14];
    unsigned long long HV0, HV1;
    short8 A0[14], A1[14];

    int t0 = blockIdx.x * 4 + wv;
    IDXP(L0, HV0, t0);
    GAT(A0, L0, HV0);                  // one exposed stall at prologue
    int t1 = t0 + GS;
    if (t1 < NTILE) IDXP(L1, HV1, t1);

    for (;;) {
        // invariant: A0 in flight for t0; L1/HV1 in flight/arrived for t1
        int t2 = t0 + 2 * GS;
        if (t2 < NTILE) IDXP(L0, HV0, t2);
        if (t1 < NTILE) GAT(A1, L1, HV1);
        __builtin_amdgcn_sched_barrier(0);
        CMP(A0, t0);
        if (t1 >= NTILE) break;

        int t3 = t1 + 2 * GS;
        if (t3 < NTILE) IDXP(L1, HV1, t3);
        if (t2 < NTILE) GAT(A0, L0, HV0);
        __builtin_amdgcn_sched_barrier(0);
        CMP(A1, t1);
        if (t2 >= NTILE) break;

        t0 = t2;
        t1 = t2 + GS;
    }

    // BN partials: per-channel sum & sumsq over all tiles this block touched
    s_acc += __shfl_xor(s_acc, 16);  s_acc += __shfl_xor(s_acc, 32);
    q_acc += __shfl_xor(q_acc, 16);  q_acc += __shfl_xor(q_acc, 32);
    if (lane < 16) {
        red[wv * 32 + rc]      = s_acc;
        red[wv * 32 + 16 + rc] = q_acc;
    }
    __syncthreads();
    if (threadIdx.x < 32) {
        float v = red[threadIdx.x] + red[32 + threadIdx.x] +
                  red[64 + threadIdx.x] + red[96 + threadIdx.x];
        partials[(size_t)threadIdx.x * CBLK + blockIdx.x] = v;
    }
}

__global__ __launch_bounds__(256) void reduce_k(const float* __restrict__ partials,
                                                float* __restrict__ S) {
    int c = blockIdx.x;  // 0..31 (16 sums, 16 sumsqs)
    float s = 0.f;
    for (int i = threadIdx.x; i < CBLK; i += 256) s += partials[(size_t)c * CBLK + i];
    __shared__ float red[256];
    red[threadIdx.x] = s;
    __syncthreads();
#pragma unroll
    for (int off = 128; off > 0; off >>= 1) {
        if (threadIdx.x < off) red[threadIdx.x] += red[threadIdx.x + off];
        __syncthreads();
    }
    if (threadIdx.x == 0) S[c] = red[0];
}

// BN finalize fused; reads raw bf16 conv output, optional bf16 residual,
// writes bf16 feature buffer and/or f32 final output. 8 elems/thread.
__global__ __launch_bounds__(256) void apply_k(const unsigned short* __restrict__ raw,
                                               const float* __restrict__ S,
                                               const float* __restrict__ gamma,
                                               const float* __restrict__ beta,
                                               const unsigned short* residb,
                                               unsigned short* bfout,
                                               float* f32out) {
    int i = (blockIdx.x * 256 + threadIdx.x) * 8;
    int c0 = i & 8;                    // channels c0..c0+7
    short8 r8 = *reinterpret_cast<const short8*>(raw + i);
    float res[8] = {0, 0, 0, 0, 0, 0, 0, 0};
    if (residb) {
        short8 x8 = *reinterpret_cast<const short8*>(residb + i);
#pragma unroll
        for (int j = 0; j < 8; ++j) res[j] = bf2f((unsigned short)x8[j]);
    }
    const float inv = 1.0f / (float)N_TOT;
    float val[8];
#pragma unroll
    for (int j = 0; j < 8; ++j) {
        int c = c0 + j;
        float m   = S[c] * inv;
        float var = S[16 + c] * inv - m * m;
        float sc  = gamma[c] * rsqrtf(var + 1e-3f);
        float sh  = beta[c] - m * sc;
        val[j] = fmaxf(bf2f((unsigned short)r8[j]) * sc + sh + res[j], 0.f);
    }
    if (bfout) {
        short8 o = { (short)f2bf(val[0]), (short)f2bf(val[1]), (short)f2bf(val[2]), (short)f2bf(val[3]),
                     (short)f2bf(val[4]), (short)f2bf(val[5]), (short)f2bf(val[6]), (short)f2bf(val[7]) };
        *reinterpret_cast<short8*>(bfout + i) = o;
    }
    if (f32out) {
        f32x4 lo = { val[0], val[1], val[2], val[3] };
        f32x4 hi = { val[4], val[5], val[6], val[7] };
        *reinterpret_cast<f32x4*>(f32out + i)     = lo;
        *reinterpret_cast<f32x4*>(f32out + i + 4) = hi;
    }
}

extern "C" void kernel_launch(void* const* d_in, const int* in_sizes, int n_in,
                              void* d_out, int out_size, void* d_ws, size_t ws_size,
                              hipStream_t stream) {
    const float* vf   = (const float*)d_in[0];
    const int*   nbr  = (const int*)  d_in[1];
    const float* w_in = (const float*)d_in[2];
    const float* g_in = (const float*)d_in[3];
    const float* b_in = (const float*)d_in[4];
    const float* wbs  = (const float*)d_in[5];
    const float* gs   = (const float*)d_in[6];
    const float* bs   = (const float*)d_in[7];
    float* out = (float*)d_out;

    char* ws = (char*)d_ws;
    size_t off = 0;
    auto alloc = [&](size_t b) { char* p = ws + off; off += (b + 255) & ~(size_t)255; return p; };
    unsigned short* wfrag = (unsigned short*)alloc((size_t)5 * 14 * 64 * 8 * 2);
    unsigned short* xb    = (unsigned short*)alloc((size_t)(NELEM + 16) * 2);  // bf16 x (+zero voxel)
    unsigned short* ob    = (unsigned short*)alloc((size_t)(NELEM + 16) * 2);  // bf16 o (+zero voxel)
    unsigned short* rb    = (unsigned short*)alloc((size_t)NELEM * 2);         // bf16 raw conv out
    char*           pk    = alloc((size_t)NTILE * PKB);                        // 28.8 MB packed rulebook
    float*          part  = (float*)alloc((size_t)32 * CBLK * 4);
    float*          S     = (float*)alloc(32 * 4);

    const int FR = 14 * 64 * 8;  // ushorts per layer of wfrag

    build_k<<<1563, 256, 0, stream>>>(nbr, pk);
    prep_k<<<3196, 256, 0, stream>>>(vf, w_in, wbs, xb, ob, wfrag);

    // L0: x0 = relu(bn(conv(vf)))                 -> xb
    conv_k<<<CBLK, 256, 0, stream>>>(xb, pk, wfrag, rb, part);
    reduce_k<<<32, 256, 0, stream>>>(part, S);
    apply_k<<<3125, 256, 0, stream>>>(rb, S, g_in, b_in, nullptr, xb, nullptr);

    // L1: o = relu(bn(conv(x0)))                  -> ob
    conv_k<<<CBLK, 256, 0, stream>>>(xb, pk, wfrag + FR, rb, part);
    reduce_k<<<32, 256, 0, stream>>>(part, S);
    apply_k<<<3125, 256, 0, stream>>>(rb, S, gs + 0, bs + 0, nullptr, ob, nullptr);

    // L2: x1 = relu(bn(conv(o)) + x0)             -> xb (in place resid)
    conv_k<<<CBLK, 256, 0, stream>>>(ob, pk, wfrag + 2 * FR, rb, part);
    reduce_k<<<32, 256, 0, stream>>>(part, S);
    apply_k<<<3125, 256, 0, stream>>>(rb, S, gs + 16, bs + 16, xb, xb, nullptr);

    // L3: o = relu(bn(conv(x1)))                  -> ob
    conv_k<<<CBLK, 256, 0, stream>>>(xb, pk, wfrag + 3 * FR, rb, part);
    reduce_k<<<32, 256, 0, stream>>>(part, S);
    apply_k<<<3125, 256, 0, stream>>>(rb, S, gs + 32, bs + 32, nullptr, ob, nullptr);

    // L4: out = relu(bn(conv(o)) + x1)            -> d_out (f32)
    conv_k<<<CBLK, 256, 0, stream>>>(ob, pk, wfrag + 4 * FR, rb, part);
    reduce_k<<<32, 256, 0, stream>>>(part, S);
    apply_k<<<3125, 256, 0, stream>>>(rb, S, gs + 48, bs + 48, xb, nullptr, out);
}

// Round 15
// 151.236 us; speedup vs baseline: 1.5717x; 1.1991x over previous
//
#include <hip/hip_runtime.h>

#define N_TOT  400000
#define NTILE  25000        // N_TOT / 16 voxels per tile
#define NELEM  (N_TOT * 16)
#define CBLK   512          // persistent conv blocks (2 per CU)
#define GS     (CBLK * 4)   // wave grid stride (tiles)

typedef __attribute__((ext_vector_type(8))) short short8;
typedef __attribute__((ext_vector_type(4))) float f32x4;
typedef __attribute__((ext_vector_type(4))) unsigned short us4;

__device__ __forceinline__ unsigned short f2bf(float x) {
    unsigned int u = __float_as_uint(x);
    u += 0x7FFFu + ((u >> 16) & 1u);       // round-to-nearest-even
    return (unsigned short)(u >> 16);
}
__device__ __forceinline__ float bf2f(unsigned short h) {
    return __uint_as_float(((unsigned int)h) << 16);
}

// Merged prep: blocks 0..3124 cvt f32->bf16; 3125..3194 build W-fragments for
// all 5 layers x 14 k-pairs (fragment (lane,slot)->element: lane l slot j ->
// W[2p+(l>>5)][((l>>4)&1)*8+j][l&15], used as the MFMA A-operand after the
// operand swap); block 3195 zeroes the pad voxel (index N_TOT) in xb/ob and
// the 5 per-layer S8 atomic-partial slots (replay-safe reset each launch).
__global__ __launch_bounds__(256) void prep_k(const float* __restrict__ vf,
                                              const float* __restrict__ w_in,
                                              const float* __restrict__ wbs,
                                              unsigned short* __restrict__ xb,
                                              unsigned short* __restrict__ ob,
                                              unsigned short* __restrict__ wfrag,
                                              unsigned long long* __restrict__ S8) {
    int b = blockIdx.x;
    if (b < 3125) {
        int i = (b * 256 + threadIdx.x) * 8;
        f32x4 a = *reinterpret_cast<const f32x4*>(vf + i);
        f32x4 c = *reinterpret_cast<const f32x4*>(vf + i + 4);
        short8 o = { (short)f2bf(a[0]), (short)f2bf(a[1]), (short)f2bf(a[2]), (short)f2bf(a[3]),
                     (short)f2bf(c[0]), (short)f2bf(c[1]), (short)f2bf(c[2]), (short)f2bf(c[3]) };
        *reinterpret_cast<short8*>(xb + i) = o;
    } else if (b < 3195) {
        if (threadIdx.x >= 64) return;
        int wb = b - 3125;               // L*14 + p
        int L = wb / 14, p = wb % 14;
        int l = threadIdx.x;
        int g = l >> 4, col = l & 15;
        int k = 2 * p + (g >> 1);
        int cib = (g & 1) * 8;
        unsigned short v[8];
#pragma unroll
        for (int j = 0; j < 8; ++j) {
            float w = 0.f;
            if (k < 27) {
                int ci = cib + j;
                w = (L == 0) ? w_in[(k * 16 + ci) * 16 + col]
                             : wbs[(((L - 1) * 27 + k) * 16 + ci) * 16 + col];
            }
            v[j] = f2bf(w);
        }
        unsigned short* dst = wfrag + (size_t)(wb * 64 + l) * 8;
#pragma unroll
        for (int j = 0; j < 8; ++j) dst[j] = v[j];
    } else {
        if (threadIdx.x < 8) {
            us4 z = {0, 0, 0, 0};
            unsigned short* base = (threadIdx.x < 4) ? xb : ob;
            reinterpret_cast<us4*>(base + NELEM)[threadIdx.x & 3] = z;
        }
        for (int i = threadIdx.x; i < 5 * 8 * 32; i += 256) S8[i] = 0ull;
    }
}

// Persistent gather-MFMA conv, 3-stage decoupled pipeline (champion structure):
//   idx loads tile t+2S | gathers tile t+S | MFMA+store tile t.
// Operand swap: W = A-operand (registers), gathered features = B-operand ->
// each lane's 4 acc values are 4 contiguous CHANNELS of voxel rc -> single
// packed 8B store. Center (k=13) = identity (no load); invalid -> zero voxel
// at N_TOT (coalesced broadcast line). BN partials: per-channel lane
// accumulators, block-reduced, then 32 scaled-int64 atomicAdds (exact-
// commutative -> deterministic) into this layer's S8 slot. No reduce kernel.
#define IDX(I, tt)                                                              \
  {                                                                             \
    const int vv = (tt) * 16;                                                   \
    _Pragma("unroll")                                                           \
    for (int p = 0; p < 14; ++p) {                                              \
      int k = 2 * p + ksel;                                                     \
      if (k == 13)      I[p] = vv + rc;                                         \
      else if (k < 27)  I[p] = nbr[(size_t)k * N_TOT + vv + rc];                \
      else              I[p] = -1;                                              \
    }                                                                           \
  }

#define GAT(A, I)                                                               \
  {                                                                             \
    _Pragma("unroll")                                                           \
    for (int p = 0; p < 14; ++p) {                                              \
      int ci = I[p] < 0 ? N_TOT : I[p];                                         \
      A[p] = *reinterpret_cast<const short8*>(feats + ((size_t)ci << 4) + half);\
    }                                                                           \
  }

#define CMP(A, tt)                                                              \
  {                                                                             \
    f32x4 ac0 = {0.f, 0.f, 0.f, 0.f};                                           \
    f32x4 ac1 = {0.f, 0.f, 0.f, 0.f};                                           \
    _Pragma("unroll")                                                           \
    for (int p = 0; p < 14; p += 2) {                                           \
      ac0 = __builtin_amdgcn_mfma_f32_16x16x32_bf16(W[p],     A[p],     ac0, 0, 0, 0); \
      ac1 = __builtin_amdgcn_mfma_f32_16x16x32_bf16(W[p + 1], A[p + 1], ac1, 0, 0, 0); \
    }                                                                           \
    f32x4 acc = ac0 + ac1;                                                      \
    const int vv = (tt) * 16;                                                   \
    us4 pk = { f2bf(acc[0]), f2bf(acc[1]), f2bf(acc[2]), f2bf(acc[3]) };        \
    *reinterpret_cast<us4*>(raw + ((size_t)(vv + rc) * 16 + hi * 4)) = pk;      \
    _Pragma("unroll")                                                           \
    for (int i = 0; i < 4; ++i) {                                               \
      s_acc[i] += acc[i];                                                       \
      q_acc[i] += acc[i] * acc[i];                                              \
    }                                                                           \
  }

__global__ __launch_bounds__(256, 2) void conv_k(const unsigned short* __restrict__ feats,
                                                 const int* __restrict__ nbr,
                                                 const unsigned short* __restrict__ wfrag,
                                                 unsigned short* __restrict__ raw,
                                                 unsigned long long* __restrict__ S8) {
    __shared__ float red[128];

    const int lane = threadIdx.x & 63;
    const int wv   = threadIdx.x >> 6;
    const int hi   = lane >> 4;        // fragment k-block / output channel group
    const int rc   = lane & 15;        // voxel within tile
    const int half = (hi & 1) * 8;     // which 8 input channels this lane loads
    const int ksel = hi >> 1;          // which offset of the pair

    // loop-invariant W-fragments: 14 x short8 = 56 VGPRs, loaded once per wave
    short8 W[14];
#pragma unroll
    for (int p = 0; p < 14; ++p)
        W[p] = *reinterpret_cast<const short8*>(wfrag + (size_t)(p * 64 + lane) * 8);

    float s_acc[4] = {0.f, 0.f, 0.f, 0.f};
    float q_acc[4] = {0.f, 0.f, 0.f, 0.f};

    int I0[14], I1[14];
    short8 A0[14], A1[14];

    int t0 = blockIdx.x * 4 + wv;
    IDX(I0, t0);
    GAT(A0, I0);                       // one exposed stall at prologue
    int t1 = t0 + GS;
    if (t1 < NTILE) IDX(I1, t1);

    for (;;) {
        // invariant: A0 in flight for t0; I1 in flight/arrived for t1
        int t2 = t0 + 2 * GS;
        if (t2 < NTILE) IDX(I0, t2);
        if (t1 < NTILE) GAT(A1, I1);
        __builtin_amdgcn_sched_barrier(0);
        CMP(A0, t0);
        if (t1 >= NTILE) break;

        int t3 = t1 + 2 * GS;
        if (t3 < NTILE) IDX(I1, t3);
        if (t2 < NTILE) GAT(A0, I0);
        __builtin_amdgcn_sched_barrier(0);
        CMP(A1, t1);
        if (t2 >= NTILE) break;

        t0 = t2;
        t1 = t2 + GS;
    }

    // BN partials: lane (hi,rc) holds channels hi*4+i summed over its voxels;
    // reduce over rc within each 16-lane group, across waves via LDS, then 32
    // scaled-int64 atomics (8 shadow copies spread contention).
#pragma unroll
    for (int i = 0; i < 4; ++i) {
        s_acc[i] += __shfl_xor(s_acc[i], 1);  s_acc[i] += __shfl_xor(s_acc[i], 2);
        s_acc[i] += __shfl_xor(s_acc[i], 4);  s_acc[i] += __shfl_xor(s_acc[i], 8);
        q_acc[i] += __shfl_xor(q_acc[i], 1);  q_acc[i] += __shfl_xor(q_acc[i], 2);
        q_acc[i] += __shfl_xor(q_acc[i], 4);  q_acc[i] += __shfl_xor(q_acc[i], 8);
    }
    if (rc == 0) {
#pragma unroll
        for (int i = 0; i < 4; ++i) {
            red[wv * 32 + hi * 4 + i]      = s_acc[i];
            red[wv * 32 + 16 + hi * 4 + i] = q_acc[i];
        }
    }
    __syncthreads();
    if (threadIdx.x < 32) {
        float v = red[threadIdx.x] + red[32 + threadIdx.x] +
                  red[64 + threadIdx.x] + red[96 + threadIdx.x];
        long long qv = llrintf(v * (threadIdx.x < 16 ? 65536.0f : 16384.0f));
        atomicAdd(&S8[(blockIdx.x & 7) * 32 + threadIdx.x], (unsigned long long)qv);
    }
}

// BN finalize fused; sums the 8 S8 shadows inline (replaces reduce_k), reads
// raw bf16 conv output, optional bf16 residual, writes bf16 features and/or
// f32 final output. 8 elems/thread.
__global__ __launch_bounds__(256) void apply_k(const unsigned short* __restrict__ raw,
                                               const unsigned long long* __restrict__ S8,
                                               const float* __restrict__ gamma,
                                               const float* __restrict__ beta,
                                               const unsigned short* residb,
                                               unsigned short* bfout,
                                               float* f32out) {
    __shared__ float scs[16], shs[16];
    if (threadIdx.x < 16) {
        int c = threadIdx.x;
        long long ss = 0, qq = 0;
#pragma unroll
        for (int j = 0; j < 8; ++j) {
            ss += (long long)S8[j * 32 + c];
            qq += (long long)S8[j * 32 + 16 + c];
        }
        float s = (float)ss * (1.0f / 65536.0f);
        float q = (float)qq * (1.0f / 16384.0f);
        const float invN = 1.0f / (float)N_TOT;
        float m   = s * invN;
        float var = q * invN - m * m;
        float sc  = gamma[c] * rsqrtf(var + 1e-3f);
        scs[c] = sc;
        shs[c] = beta[c] - m * sc;
    }
    __syncthreads();
    int i = (blockIdx.x * 256 + threadIdx.x) * 8;
    int c0 = i & 8;                    // channels c0..c0+7
    short8 r8 = *reinterpret_cast<const short8*>(raw + i);
    float res[8] = {0, 0, 0, 0, 0, 0, 0, 0};
    if (residb) {
        short8 x8 = *reinterpret_cast<const short8*>(residb + i);
#pragma unroll
        for (int j = 0; j < 8; ++j) res[j] = bf2f((unsigned short)x8[j]);
    }
    float val[8];
#pragma unroll
    for (int j = 0; j < 8; ++j) {
        int c = c0 + j;
        val[j] = fmaxf(bf2f((unsigned short)r8[j]) * scs[c] + shs[c] + res[j], 0.f);
    }
    if (bfout) {
        short8 o = { (short)f2bf(val[0]), (short)f2bf(val[1]), (short)f2bf(val[2]), (short)f2bf(val[3]),
                     (short)f2bf(val[4]), (short)f2bf(val[5]), (short)f2bf(val[6]), (short)f2bf(val[7]) };
        *reinterpret_cast<short8*>(bfout + i) = o;
    }
    if (f32out) {
        f32x4 lo = { val[0], val[1], val[2], val[3] };
        f32x4 hi = { val[4], val[5], val[6], val[7] };
        *reinterpret_cast<f32x4*>(f32out + i)     = lo;
        *reinterpret_cast<f32x4*>(f32out + i + 4) = hi;
    }
}

extern "C" void kernel_launch(void* const* d_in, const int* in_sizes, int n_in,
                              void* d_out, int out_size, void* d_ws, size_t ws_size,
                              hipStream_t stream) {
    const float* vf   = (const float*)d_in[0];
    const int*   nbr  = (const int*)  d_in[1];
    const float* w_in = (const float*)d_in[2];
    const float* g_in = (const float*)d_in[3];
    const float* b_in = (const float*)d_in[4];
    const float* wbs  = (const float*)d_in[5];
    const float* gs   = (const float*)d_in[6];
    const float* bs   = (const float*)d_in[7];
    float* out = (float*)d_out;

    char* ws = (char*)d_ws;
    size_t off = 0;
    auto alloc = [&](size_t b) { char* p = ws + off; off += (b + 255) & ~(size_t)255; return p; };
    unsigned short*     wfrag = (unsigned short*)alloc((size_t)5 * 14 * 64 * 8 * 2);
    unsigned short*     xb    = (unsigned short*)alloc((size_t)(NELEM + 16) * 2);  // bf16 x (+zero voxel)
    unsigned short*     ob    = (unsigned short*)alloc((size_t)(NELEM + 16) * 2);  // bf16 o (+zero voxel)
    unsigned short*     rb    = (unsigned short*)alloc((size_t)NELEM * 2);         // bf16 raw conv out
    unsigned long long* S8    = (unsigned long long*)alloc((size_t)5 * 8 * 32 * 8);

    const int FR = 14 * 64 * 8;   // ushorts per layer of wfrag
    const int SL = 8 * 32;        // u64s per layer of S8

    prep_k<<<3196, 256, 0, stream>>>(vf, w_in, wbs, xb, ob, wfrag, S8);

    // L0: x0 = relu(bn(conv(vf)))                 -> xb
    conv_k<<<CBLK, 256, 0, stream>>>(xb, nbr, wfrag, rb, S8);
    apply_k<<<3125, 256, 0, stream>>>(rb, S8, g_in, b_in, nullptr, xb, nullptr);

    // L1: o = relu(bn(conv(x0)))                  -> ob
    conv_k<<<CBLK, 256, 0, stream>>>(xb, nbr, wfrag + FR, rb, S8 + SL);
    apply_k<<<3125, 256, 0, stream>>>(rb, S8 + SL, gs + 0, bs + 0, nullptr, ob, nullptr);

    // L2: x1 = relu(bn(conv(o)) + x0)             -> xb (in place resid)
    conv_k<<<CBLK, 256, 0, stream>>>(ob, nbr, wfrag + 2 * FR, rb, S8 + 2 * SL);
    apply_k<<<3125, 256, 0, stream>>>(rb, S8 + 2 * SL, gs + 16, bs + 16, xb, xb, nullptr);

    // L3: o = relu(bn(conv(x1)))                  -> ob
    conv_k<<<CBLK, 256, 0, stream>>>(xb, nbr, wfrag + 3 * FR, rb, S8 + 3 * SL);
    apply_k<<<3125, 256, 0, stream>>>(rb, S8 + 3 * SL, gs + 32, bs + 32, nullptr, ob, nullptr);

    // L4: out = relu(bn(conv(o)) + x1)            -> d_out (f32)
    conv_k<<<CBLK, 256, 0, stream>>>(ob, nbr, wfrag + 4 * FR, rb, S8 + 4 * SL);
    apply_k<<<3125, 256, 0, stream>>>(rb, S8 + 4 * SL, gs + 48, bs + 48, xb, nullptr, out);
}